// Round 1
// baseline (467.789 us; speedup 1.0000x reference)
//
#include <hip/hip_runtime.h>
#include <cstdint>
#include <cstddef>

typedef __bf16 bf16x8 __attribute__((ext_vector_type(8)));
typedef float f32x4 __attribute__((ext_vector_type(4)));
typedef unsigned short ushortx8 __attribute__((ext_vector_type(8)));

// RNE float -> bf16 (as ushort payload)
__device__ __forceinline__ unsigned short f2bf(float f) {
  union { float f; unsigned int u; } v; v.f = f;
  unsigned int u = v.u;
  unsigned int r = (u + 0x7FFFu + ((u >> 16) & 1u)) >> 16;
  return (unsigned short)r;
}

// exact-enough GELU (tanh form, max abs err ~1e-3 vs erf form)
__device__ __forceinline__ float gelu_f(float x) {
  float t = 0.7978845608f * x * (1.0f + 0.044715f * x * x);
  float e = __expf(-2.0f * fabsf(t));
  float th = (1.0f - e) / (1.0f + e);
  th = (t >= 0.0f) ? th : -th;
  return 0.5f * x * (1.0f + th);
}

// async global->LDS, 16B per lane. LDS dest must be wave-uniform base + lane*16.
#define GLOAD16(gsrc, ldst)                                                  \
  __builtin_amdgcn_global_load_lds(                                          \
      (const __attribute__((address_space(1))) unsigned int*)(gsrc),         \
      (__attribute__((address_space(3))) unsigned int*)(uintptr_t)(          \
          (char*)(ldst)),                                                    \
      16, 0, 0)

// ---------------------------------------------------------------------------
// Conversion: z -> bf16 [B,512]; W1[g,d,h] -> W1t[g,h,d] bf16; Wc[d,g] -> Wct[g,d]
// ---------------------------------------------------------------------------
__global__ __launch_bounds__(256) void k_convert(
    const float* __restrict__ z, const float* __restrict__ W1,
    const float* __restrict__ Wc, unsigned short* __restrict__ zb,
    unsigned short* __restrict__ w1t, unsigned short* __restrict__ wct) {
  int bid = blockIdx.x;
  int tid = threadIdx.x;
  if (bid < 16384) {
    // z: 8 floats/thread, 16384*256*8 = 33,554,432 = 65536*512
    size_t i = ((size_t)bid * 256 + tid) * 8;
    const float4* p = (const float4*)(z + i);
    float4 a = p[0], b = p[1];
    ushortx8 r;
    r[0] = f2bf(a.x); r[1] = f2bf(a.y); r[2] = f2bf(a.z); r[3] = f2bf(a.w);
    r[4] = f2bf(b.x); r[5] = f2bf(b.y); r[6] = f2bf(b.z); r[7] = f2bf(b.w);
    *(ushortx8*)(zb + i) = r;
  } else if (bid < 16384 + 4096) {
    // W1 transpose: out idx = g*65536 + h*512 + d  (writes coalesced)
    int i = (bid - 16384) * 256 + tid;  // 0 .. 1,048,575
    int d = i & 511;
    int h = (i >> 9) & 127;
    int gg = i >> 16;
    w1t[i] = f2bf(W1[(gg << 16) + d * 128 + h]);
  } else {
    // Wc transpose: wct[g*512+d] = Wc[d*16+g], 8192 elems
    int i = (bid - 20480) * 256 + tid;
    int gg = i >> 9;
    int d = i & 511;
    wct[i] = f2bf(Wc[d * 16 + gg]);
  }
}

// ---------------------------------------------------------------------------
// Fused main kernel. grid = 512 m-tiles x 17 (g<16: expert block, g==16: logits)
// ---------------------------------------------------------------------------
__global__ __launch_bounds__(256, 2) void k_main(
    const unsigned short* __restrict__ zb,   // [65536][512] bf16
    const unsigned short* __restrict__ w1t,  // [16][128][512] bf16
    const unsigned short* __restrict__ wct,  // [16][512] bf16
    const float* __restrict__ bc, const float* __restrict__ b1,
    const float* __restrict__ w2, const float* __restrict__ b2,
    float* __restrict__ out) {
  __shared__ alignas(16) char lds[16384 + 16384 + 1024];
  const int tid = threadIdx.x;
  const int g = blockIdx.x % 17;
  const int m = blockIdx.x / 17;
  const int mbase = m * 128;
  const int wv = tid >> 6;
  const int ln = tid & 63;
  const int l15 = ln & 15;
  const int l4 = ln >> 4;

  // A staging source: row = mbase + it*32 + tid/8, col = kt*64 + (tid&7)*8
  const unsigned short* ag =
      zb + (size_t)(mbase + (tid >> 3)) * 512 + (tid & 7) * 8;

  if (g < 16) {
    // ---------------- expert block: C = z_tile @ W1_g, gelu, dot W2 --------
    const unsigned short* bg =
        w1t + g * 65536 + (tid >> 3) * 512 + (tid & 7) * 8;
    const int rh = (wv >> 1) * 64;  // row half of this wave
    const int ch = (wv & 1) * 64;   // col half of this wave
    f32x4 acc[4][4] = {};
    for (int kt = 0; kt < 8; ++kt) {
      const int ko = kt * 64;
#pragma unroll
      for (int it = 0; it < 4; ++it) {
        GLOAD16(ag + (size_t)it * 32 * 512 + ko, lds + it * 4096 + tid * 16);
        GLOAD16(bg + it * 32 * 512 + ko,
                lds + 16384 + it * 4096 + tid * 16);
      }
      __syncthreads();  // compiler drains vmcnt(0) here
      bf16x8 af[4][2], bfv[4][2];
#pragma unroll
      for (int rt = 0; rt < 4; ++rt)
#pragma unroll
        for (int ks = 0; ks < 2; ++ks)
          af[rt][ks] = *(const bf16x8*)(lds + (rh + rt * 16 + l15) * 128 +
                                        (ks * 32 + l4 * 8) * 2);
#pragma unroll
      for (int ct = 0; ct < 4; ++ct)
#pragma unroll
        for (int ks = 0; ks < 2; ++ks)
          bfv[ct][ks] =
              *(const bf16x8*)(lds + 16384 + (ch + ct * 16 + l15) * 128 +
                               (ks * 32 + l4 * 8) * 2);
#pragma unroll
      for (int rt = 0; rt < 4; ++rt)
#pragma unroll
        for (int ct = 0; ct < 4; ++ct)
#pragma unroll
          for (int ks = 0; ks < 2; ++ks)
            acc[rt][ct] = __builtin_amdgcn_mfma_f32_16x16x32_bf16(
                af[rt][ks], bfv[ct][ks], acc[rt][ct], 0, 0, 0);
      __syncthreads();
    }
    // epilogue: y[row] = sum_n gelu(h+b1)*W2 + b2
    float b1v[4], w2v[4];
#pragma unroll
    for (int ct = 0; ct < 4; ++ct) {
      int n = ch + ct * 16 + l15;
      b1v[ct] = b1[g * 128 + n];
      w2v[ct] = w2[g * 128 + n];
    }
    float* ylds = (float*)(lds + 32768);  // [2 col-halves][128 rows]
#pragma unroll
    for (int rt = 0; rt < 4; ++rt) {
#pragma unroll
      for (int i = 0; i < 4; ++i) {
        float s = 0.0f;
#pragma unroll
        for (int ct = 0; ct < 4; ++ct) {
          float x = acc[rt][ct][i] + b1v[ct];
          s += gelu_f(x) * w2v[ct];
        }
#pragma unroll
        for (int off = 1; off < 16; off <<= 1)
          s += __shfl_xor(s, off, 16);
        if (l15 == 0) ylds[(wv & 1) * 128 + rh + rt * 16 + l4 * 4 + i] = s;
      }
    }
    __syncthreads();
    if (tid < 128) {
      float y = ylds[tid] + ylds[128 + tid] + b2[g];
      out[(size_t)2097152 + (size_t)(mbase + tid) * 16 + g] = y;
    }
  } else {
    // ---------------- logits block: logits = z_tile @ Wc + bc, softmax ----
    // preload whole Wct (16 KB) into B region once
#pragma unroll
    for (int it = 0; it < 4; ++it)
      GLOAD16(wct + it * 2048 + tid * 8, lds + 16384 + it * 4096 + tid * 16);
    f32x4 acc2[2] = {};
    for (int kt = 0; kt < 8; ++kt) {
      const int ko = kt * 64;
#pragma unroll
      for (int it = 0; it < 4; ++it)
        GLOAD16(ag + (size_t)it * 32 * 512 + ko, lds + it * 4096 + tid * 16);
      __syncthreads();
      bf16x8 bfr[2];
#pragma unroll
      for (int ks = 0; ks < 2; ++ks)
        bfr[ks] = *(const bf16x8*)(lds + 16384 + l15 * 1024 +
                                   (ko + ks * 32 + l4 * 8) * 2);
#pragma unroll
      for (int rt = 0; rt < 2; ++rt)
#pragma unroll
        for (int ks = 0; ks < 2; ++ks) {
          bf16x8 af = *(const bf16x8*)(lds + (wv * 32 + rt * 16 + l15) * 128 +
                                       (ks * 32 + l4 * 8) * 2);
          acc2[rt] = __builtin_amdgcn_mfma_f32_16x16x32_bf16(af, bfr[ks],
                                                             acc2[rt], 0, 0, 0);
        }
      __syncthreads();
    }
    float bcv = bc[l15];
#pragma unroll
    for (int rt = 0; rt < 2; ++rt) {
#pragma unroll
      for (int i = 0; i < 4; ++i) {
        int row = wv * 32 + rt * 16 + l4 * 4 + i;
        float lg = acc2[rt][i] + bcv;
        float mx = lg;
#pragma unroll
        for (int off = 1; off < 16; off <<= 1)
          mx = fmaxf(mx, __shfl_xor(mx, off, 16));
        float e = __expf(lg - mx);
        float sm = e;
#pragma unroll
        for (int off = 1; off < 16; off <<= 1)
          sm += __shfl_xor(sm, off, 16);
        size_t ro = (size_t)(mbase + row) * 16 + l15;
        out[ro] = lg;                  // logits
        out[1048576 + ro] = e / sm;    // p_g
      }
    }
  }
}

// ---------------------------------------------------------------------------
extern "C" void kernel_launch(void* const* d_in, const int* in_sizes, int n_in,
                              void* d_out, int out_size, void* d_ws,
                              size_t ws_size, hipStream_t stream) {
  const float* z = (const float*)d_in[0];
  const float* Wc = (const float*)d_in[1];
  const float* bc = (const float*)d_in[2];
  const float* W1 = (const float*)d_in[3];
  const float* b1 = (const float*)d_in[4];
  const float* W2 = (const float*)d_in[5];
  const float* b2 = (const float*)d_in[6];
  float* out = (float*)d_out;

  // workspace layout: zb (64 MB) | w1t (2 MB) | wct (16 KB)
  unsigned short* zb = (unsigned short*)d_ws;
  unsigned short* w1t = zb + (size_t)65536 * 512;
  unsigned short* wct = w1t + (size_t)16 * 128 * 512;

  k_convert<<<16384 + 4096 + 32, 256, 0, stream>>>(z, W1, Wc, zb, w1t, wct);
  k_main<<<512 * 17, 256, 0, stream>>>(zb, w1t, wct, bc, b1, W2, b2, out);
}

// Round 2
// 418.852 us; speedup vs baseline: 1.1168x; 1.1168x over previous
//
#include <hip/hip_runtime.h>
#include <cstdint>
#include <cstddef>

typedef __bf16 bf16x8 __attribute__((ext_vector_type(8)));
typedef float f32x4 __attribute__((ext_vector_type(4)));
typedef unsigned short ushortx8 __attribute__((ext_vector_type(8)));

// float -> bf16, round-half-up (differs from RNE only on exact ties)
__device__ __forceinline__ unsigned short f2bf(float f) {
  union { float f; unsigned int u; } v; v.f = f;
  return (unsigned short)((v.u + 0x8000u) >> 16);
}

// GELU tanh form (max abs err ~1e-3 vs erf form; tolerance is ~2e-2+)
__device__ __forceinline__ float gelu_f(float x) {
  float t = 0.7978845608f * x * (1.0f + 0.044715f * x * x);
  float e = __expf(-2.0f * fabsf(t));
  float th = (1.0f - e) / (1.0f + e);
  th = (t >= 0.0f) ? th : -th;
  return 0.5f * x * (1.0f + th);
}

// async global->LDS, 16B/lane. LDS dest is wave-uniform base + lane*16.
#define GLOAD16(gsrc, ldst)                                                  \
  __builtin_amdgcn_global_load_lds(                                          \
      (const __attribute__((address_space(1))) unsigned int*)(gsrc),         \
      (__attribute__((address_space(3))) unsigned int*)(uintptr_t)(          \
          (char*)(ldst)),                                                    \
      16, 0, 0)

// Swizzled tile: 16B chunk (row R in [0,128), col8 C in [0,8)) lives at
// chunk (R>>5)*4096 + slot ((R&31)*8 + (C ^ (R&7)))*16.  Staging lane tid
// (slot tid within chunk) therefore sources col8 (tid&7)^((tid>>3)&7);
// fragment reads by 16 consecutive rows spread across all 8 bank quads
// (2-way residual alias only -> conflict-free per m136).
#define SWZ_FRAG(base, R, C8)                                                \
  (*(const bf16x8*)((base) + (((R) >> 5) * 4096) +                           \
                    ((((R)&31) * 8 + ((C8) ^ ((R)&7))) * 16)))

// ---------------------------------------------------------------------------
// Conversion: z -> bf16 [B,512]; W1[g,d,h] -> W1t[g,h,d] bf16; Wc[d,g] -> Wct[g,d]
// ---------------------------------------------------------------------------
__global__ __launch_bounds__(256) void k_convert(
    const float* __restrict__ z, const float* __restrict__ W1,
    const float* __restrict__ Wc, unsigned short* __restrict__ zb,
    unsigned short* __restrict__ w1t, unsigned short* __restrict__ wct) {
  int bid = blockIdx.x;
  int tid = threadIdx.x;
  if (bid < 16384) {
    // z: 8 floats/thread, 16384*256*8 = 33,554,432 = 65536*512
    size_t i = ((size_t)bid * 256 + tid) * 8;
    const float4* p = (const float4*)(z + i);
    float4 a = p[0], b = p[1];
    ushortx8 r;
    r[0] = f2bf(a.x); r[1] = f2bf(a.y); r[2] = f2bf(a.z); r[3] = f2bf(a.w);
    r[4] = f2bf(b.x); r[5] = f2bf(b.y); r[6] = f2bf(b.z); r[7] = f2bf(b.w);
    *(ushortx8*)(zb + i) = r;
  } else if (bid < 16384 + 4096) {
    // W1 transpose: out idx = g*65536 + h*512 + d  (writes coalesced)
    int i = (bid - 16384) * 256 + tid;  // 0 .. 1,048,575
    int d = i & 511;
    int h = (i >> 9) & 127;
    int gg = i >> 16;
    w1t[i] = f2bf(W1[(gg << 16) + d * 128 + h]);
  } else {
    // Wc transpose: wct[g*512+d] = Wc[d*16+g], 8192 elems
    int i = (bid - 20480) * 256 + tid;
    int gg = i >> 9;
    int d = i & 511;
    wct[i] = f2bf(Wc[d * 16 + gg]);
  }
}

// ---------------------------------------------------------------------------
// Fused main kernel. grid = 512 m-tiles x 17 (g<16: expert block, g==16: logits)
// ---------------------------------------------------------------------------
__global__ __launch_bounds__(256, 2) void k_main(
    const unsigned short* __restrict__ zb,   // [65536][512] bf16
    const unsigned short* __restrict__ w1t,  // [16][128][512] bf16
    const unsigned short* __restrict__ wct,  // [16][512] bf16
    const float* __restrict__ bc, const float* __restrict__ b1,
    const float* __restrict__ w2, const float* __restrict__ b2,
    float* __restrict__ out) {
  __shared__ alignas(16) char lds[16384 + 16384 + 1024];
  const int tid = threadIdx.x;
  const int g = blockIdx.x % 17;
  const int m = blockIdx.x / 17;
  const int mbase = m * 128;
  const int wv = tid >> 6;
  const int ln = tid & 63;
  const int l15 = ln & 15;
  const int l4 = ln >> 4;

  // staging source: row = mbase + it*32 + tid/8, col8 swizzled by row&7
  const int c8s = (((tid & 7) ^ ((tid >> 3) & 7))) * 8;  // element offset
  const unsigned short* ag = zb + (size_t)(mbase + (tid >> 3)) * 512 + c8s;

  if (g < 16) {
    // ---------------- expert block: C = z_tile @ W1_g^T, gelu, dot W2 ------
    const unsigned short* bg = w1t + g * 65536 + (tid >> 3) * 512 + c8s;
    const int rh = (wv >> 1) * 64;  // row half of this wave
    const int ch = (wv & 1) * 64;   // col half of this wave
    f32x4 acc[4][4] = {};
    for (int kt = 0; kt < 8; ++kt) {
      const int ko = kt * 64;
#pragma unroll
      for (int it = 0; it < 4; ++it) {
        GLOAD16(ag + (size_t)it * 32 * 512 + ko, lds + it * 4096 + tid * 16);
        GLOAD16(bg + it * 32 * 512 + ko,
                lds + 16384 + it * 4096 + tid * 16);
      }
      __syncthreads();  // compiler drains vmcnt(0) here
      bf16x8 af[4][2], bfv[4][2];
#pragma unroll
      for (int rt = 0; rt < 4; ++rt)
#pragma unroll
        for (int ks = 0; ks < 2; ++ks)
          af[rt][ks] = SWZ_FRAG(lds, rh + rt * 16 + l15, ks * 4 + l4);
#pragma unroll
      for (int ct = 0; ct < 4; ++ct)
#pragma unroll
        for (int ks = 0; ks < 2; ++ks)
          bfv[ct][ks] =
              SWZ_FRAG(lds + 16384, ch + ct * 16 + l15, ks * 4 + l4);
#pragma unroll
      for (int rt = 0; rt < 4; ++rt)
#pragma unroll
        for (int ct = 0; ct < 4; ++ct)
#pragma unroll
          for (int ks = 0; ks < 2; ++ks)
            acc[rt][ct] = __builtin_amdgcn_mfma_f32_16x16x32_bf16(
                af[rt][ks], bfv[ct][ks], acc[rt][ct], 0, 0, 0);
      __syncthreads();
    }
    // epilogue: y[row] = sum_n gelu(h+b1)*W2 + b2
    float b1v[4], w2v[4];
#pragma unroll
    for (int ct = 0; ct < 4; ++ct) {
      int n = ch + ct * 16 + l15;
      b1v[ct] = b1[g * 128 + n];
      w2v[ct] = w2[g * 128 + n];
    }
    float* ylds = (float*)(lds + 32768);  // [2 col-halves][128 rows]
#pragma unroll
    for (int rt = 0; rt < 4; ++rt) {
#pragma unroll
      for (int i = 0; i < 4; ++i) {
        float s = 0.0f;
#pragma unroll
        for (int ct = 0; ct < 4; ++ct) {
          float x = acc[rt][ct][i] + b1v[ct];
          s += gelu_f(x) * w2v[ct];
        }
#pragma unroll
        for (int off = 1; off < 16; off <<= 1)
          s += __shfl_xor(s, off, 16);
        if (l15 == 0) ylds[(wv & 1) * 128 + rh + rt * 16 + l4 * 4 + i] = s;
      }
    }
    __syncthreads();
    if (tid < 128) {
      float y = ylds[tid] + ylds[128 + tid] + b2[g];
      out[(size_t)2097152 + (size_t)(mbase + tid) * 16 + g] = y;
    }
  } else {
    // ---------------- logits block: logits = z_tile @ Wc + bc, softmax ----
    // preload whole Wct (16 KB) into B region once (unswizzled)
#pragma unroll
    for (int it = 0; it < 4; ++it)
      GLOAD16(wct + it * 2048 + tid * 8, lds + 16384 + it * 4096 + tid * 16);
    f32x4 acc2[2] = {};
    for (int kt = 0; kt < 8; ++kt) {
      const int ko = kt * 64;
#pragma unroll
      for (int it = 0; it < 4; ++it)
        GLOAD16(ag + (size_t)it * 32 * 512 + ko, lds + it * 4096 + tid * 16);
      __syncthreads();
      bf16x8 bfr[2];
#pragma unroll
      for (int ks = 0; ks < 2; ++ks)
        bfr[ks] = *(const bf16x8*)(lds + 16384 + l15 * 1024 +
                                   (ko + ks * 32 + l4 * 8) * 2);
#pragma unroll
      for (int rt = 0; rt < 2; ++rt)
#pragma unroll
        for (int ks = 0; ks < 2; ++ks) {
          bf16x8 af = SWZ_FRAG(lds, wv * 32 + rt * 16 + l15, ks * 4 + l4);
          acc2[rt] = __builtin_amdgcn_mfma_f32_16x16x32_bf16(af, bfr[ks],
                                                             acc2[rt], 0, 0, 0);
        }
      __syncthreads();
    }
    float bcv = bc[l15];
#pragma unroll
    for (int rt = 0; rt < 2; ++rt) {
#pragma unroll
      for (int i = 0; i < 4; ++i) {
        int row = wv * 32 + rt * 16 + l4 * 4 + i;
        float lg = acc2[rt][i] + bcv;
        float mx = lg;
#pragma unroll
        for (int off = 1; off < 16; off <<= 1)
          mx = fmaxf(mx, __shfl_xor(mx, off, 16));
        float e = __expf(lg - mx);
        float sm = e;
#pragma unroll
        for (int off = 1; off < 16; off <<= 1)
          sm += __shfl_xor(sm, off, 16);
        size_t ro = (size_t)(mbase + row) * 16 + l15;
        out[ro] = lg;                  // logits
        out[1048576 + ro] = e / sm;    // p_g
      }
    }
  }
}

// ---------------------------------------------------------------------------
extern "C" void kernel_launch(void* const* d_in, const int* in_sizes, int n_in,
                              void* d_out, int out_size, void* d_ws,
                              size_t ws_size, hipStream_t stream) {
  const float* z = (const float*)d_in[0];
  const float* Wc = (const float*)d_in[1];
  const float* bc = (const float*)d_in[2];
  const float* W1 = (const float*)d_in[3];
  const float* b1 = (const float*)d_in[4];
  const float* W2 = (const float*)d_in[5];
  const float* b2 = (const float*)d_in[6];
  float* out = (float*)d_out;

  // workspace layout: zb (64 MB) | w1t (2 MB) | wct (16 KB)
  unsigned short* zb = (unsigned short*)d_ws;
  unsigned short* w1t = zb + (size_t)65536 * 512;
  unsigned short* wct = w1t + (size_t)16 * 128 * 512;

  k_convert<<<16384 + 4096 + 32, 256, 0, stream>>>(z, W1, Wc, zb, w1t, wct);
  k_main<<<512 * 17, 256, 0, stream>>>(zb, w1t, wct, bc, b1, W2, b2, out);
}